// Round 18
// baseline (104.160 us; speedup 1.0000x reference)
//
#include <hip/hip_runtime.h>
#include <hip/hip_bf16.h>
#include <math.h>

// Problem constants (B, N, D) = (256, 128, 128)
#define B_    256
#define N_    128
#define MAXP  30
#define OTHER_ 35
#define CIN1  131
#define NIDX  381

#define KPAD1 160
#define KPAD2 256
#define KPAD3 128
#define S_IDX (B_ * NIDX)          // 97536
#define S_P1  (15 * 2 * 8 * 512)   // 122880  (gks * NWO2 * SUB8 * 512)
#define S_P2  (24 * 2 * 4 * 512)   // 98304
#define S_P3  (12 * 2 * 2 * 512)   // 24576
#define PREP_TOTAL (S_IDX + S_P1 + S_P2 + S_P3)
#define PREP_BLOCKS ((PREP_TOTAL + 511) / 512)

typedef short short8 __attribute__((ext_vector_type(8)));
typedef float f32x4 __attribute__((ext_vector_type(4)));

// RNE split of f32 into hi/lo bf16 via bit math (prep only)
__device__ inline void split1(float v, short& h, short& l) {
  unsigned u = __float_as_uint(v);
  unsigned hb = (u + 0x7fffu + ((u >> 16) & 1u)) >> 16;
  float fh = __uint_as_float(hb << 16);
  float r = v - fh;
  unsigned u2 = __float_as_uint(r);
  unsigned lb = (u2 + 0x7fffu + ((u2 >> 16) & 1u)) >> 16;
  h = (short)hb;
  l = (short)lb;
}

// RNE split via HW cvt — hot path
__device__ inline void split2(float v, short& h, short& l) {
  __hip_bfloat16 hb = __float2bfloat16(v);
  float fh = __bfloat162float(hb);
  __hip_bfloat16 lb = __float2bfloat16(v - fh);
  __builtin_memcpy(&h, &hb, 2);
  __builtin_memcpy(&l, &lb, 2);
}

// ---------------------------------------------------------------------------
// Weight pack: l -> [gks][g][su][lane][e]; g in [0,NWO). Value w[oc][ch][kk],
// oc=(g*SUB+su)*16+(lane&15), ctot=gks*32+((lane>>4)&3)*8+e,
// kk=ctot/KPAD, ch=ctot%KPAD (0 if ch>=KREAL).
// ---------------------------------------------------------------------------
template <int KREAL, int KPAD, int SUB, int NWO>
__device__ inline void packw(int l, const float* __restrict__ w,
                             short* __restrict__ oh, short* __restrict__ ol) {
  const int e = l & 7;
  const int lane = (l >> 3) & 63;
  const int x = l >> 9;
  const int su = x % SUB;
  const int y = x / SUB;
  const int g = y % NWO;
  const int gks = y / NWO;
  const int oc = (g * SUB + su) * 16 + (lane & 15);
  const int ctot = gks * 32 + ((lane >> 4) & 3) * 8 + e;
  const int kk = ctot / KPAD;
  const int ch = ctot - kk * KPAD;
  const float v = (ch < KREAL) ? w[(oc * KREAL + ch) * 3 + kk] : 0.f;
  short h, lo;
  split1(v, h, lo);
  oh[l] = h;
  ol[l] = lo;
}

// ---------------------------------------------------------------------------
// Prep: idx convert (wave-uniform int64 detection) + weight packing only.
// ---------------------------------------------------------------------------
__global__ __launch_bounds__(512) void prep_kernel(
    const void* __restrict__ rawIdx, int* __restrict__ idx32,
    const float* __restrict__ w1, short* __restrict__ w1h, short* __restrict__ w1l,
    const float* __restrict__ w2, short* __restrict__ w2h, short* __restrict__ w2l,
    const float* __restrict__ w3, short* __restrict__ w3h, short* __restrict__ w3l) {
  const int gid = blockIdx.x * 512 + threadIdx.x;
  if (gid < S_IDX) {
    // int64 LE view is (v,0,v,0,...) with v in [0,128)
    const int* r32 = (const int*)rawIdx;
    const int lane = threadIdx.x & 63;
    const int lo = r32[2 * lane];
    const int hi = r32[2 * lane + 1];
    const bool ok = (hi == 0 && lo >= 0 && lo < N_);
    const bool is64 = __all(ok);
    idx32[gid] = is64 ? (int)((const long long*)rawIdx)[gid] : ((const int*)rawIdx)[gid];
  } else if (gid < S_IDX + S_P1) {
    packw<131, KPAD1, 8, 2>(gid - S_IDX, w1, w1h, w1l);
  } else if (gid < S_IDX + S_P1 + S_P2) {
    packw<256, KPAD2, 4, 2>(gid - (S_IDX + S_P1), w2, w2h, w2l);
  } else if (gid < PREP_TOTAL) {
    packw<128, KPAD3, 2, 2>(gid - (S_IDX + S_P1 + S_P2), w3, w3h, w3l);
  }
}

// ---------------------------------------------------------------------------
// FUSED v7 = r17 (embed in-kernel) with wave grid (wj 0..7 x wo 0..1):
// wave owns ONE 16-row j-tile (JT=1 -> A-LDS reads per gks halve) and an
// oc-HALF (SUB 8/4/2). Weight fragments re-read by 2 waves (L1-cheap).
// Block = one batch, 1024 threads. Only global write: out[b].
// ---------------------------------------------------------------------------
__global__ __launch_bounds__(1024, 1) void fused_kernel(
    const float* __restrict__ feature,
    const float* __restrict__ col_embed,   // (200,32)
    const float* __restrict__ op_embed,    // (20,32)
    const int* __restrict__ idx,
    const short* __restrict__ w1h, const short* __restrict__ w1l,
    const short* __restrict__ w2h, const short* __restrict__ w2l,
    const short* __restrict__ w3h, const short* __restrict__ w3l,
    const float* __restrict__ b1, const float* __restrict__ b2,
    const float* __restrict__ b3,
    const float* __restrict__ fw1, const float* __restrict__ fb1,
    const float* __restrict__ fw2, const float* __restrict__ fb2,
    float* __restrict__ out) {
  constexpr int CINP = 264;   // shorts per row (528 B)

  __shared__ short smem[128 * CINP * 2];   // sH | sL, 135.2 KB
  __shared__ int nb_s[NIDX];
  __shared__ double red[32];
  __shared__ float bc[2];
  __shared__ float poolw[16][32];

  short* sH = smem;
  short* sL = smem + 128 * CINP;
  float* feat = (float*)smem;                 // [128][133], aliased
  float* ceL  = ((float*)smem) + 128 * 133;   // 200x32, aliased
  float* oeL  = ceL + 200 * 32;               // 20x32

  const int b = blockIdx.x;
  const int tid = threadIdx.x;
  const int lane = tid & 63;
  const int w = tid >> 6;       // 0..15
  const int wj = w >> 1;        // 0..7
  const int wo = w & 1;         // 0..1
  const int col = lane & 15;
  const int grp = (lane >> 4) & 3;
  const int jbase = wj * 16;
  const int cl = lane & 31;

  const short8* __restrict__ wp1h = (const short8*)w1h;
  const short8* __restrict__ wp1l = (const short8*)w1l;
  const short8* __restrict__ wp2h = (const short8*)w2h;
  const short8* __restrict__ wp2l = (const short8*)w2l;
  const short8* __restrict__ wp3h = (const short8*)w3h;
  const short8* __restrict__ wp3l = (const short8*)w3l;

  auto blockStats = [&](double ss, double sq, double cnt) {
#pragma unroll
    for (int o = 32; o > 0; o >>= 1) {
      ss += __shfl_down(ss, o, 64);
      sq += __shfl_down(sq, o, 64);
    }
    if (lane == 0) { red[w * 2] = ss; red[w * 2 + 1] = sq; }
    __syncthreads();
    if (tid == 0) {
      double S = 0.0, Q = 0.0;
#pragma unroll
      for (int i = 0; i < 16; ++i) { S += red[i * 2]; Q += red[i * 2 + 1]; }
      const double m = S / cnt;
      double var = (Q - S * S / cnt) / (cnt - 1.0);
      if (var < 0.0) var = 0.0;
      bc[0] = (float)m;
      bc[1] = (float)(1.0 / (sqrt(var) + 1e-5));
    }
    __syncthreads();
  };

  // ================= PHASE E: embed =================
  {
    const float* fb = feature + (size_t)b * 16384;
#pragma unroll
    for (int it = 0; it < 4; ++it) {
      const int t = it * 1024 + tid;
      const int d = t >> 5;
      const int c4 = (t & 31) * 4;
      const float4 v = *reinterpret_cast<const float4*>(&fb[d * 128 + c4]);
      float* p = &feat[d * 133 + c4];
      p[0] = v.x; p[1] = v.y; p[2] = v.z; p[3] = v.w;
    }
    const float4* s = (const float4*)col_embed;
    float4* d4 = (float4*)ceL;
#pragma unroll
    for (int it = 0; it < 2; ++it) {
      const int t = it * 1024 + tid;
      if (t < 1600) d4[t] = s[t];
    }
    if (tid < 160) ((float4*)oeL)[tid] = ((const float4*)op_embed)[tid];
    if (tid < NIDX) nb_s[tid] = idx[b * NIDX + tid];
  }
  __syncthreads();

  // E2: per wave 8 nodes -> collate fragments in registers
  float emb[8], oth[8], par[8];
#pragma unroll
  for (int ni = 0; ni < 8; ++ni) {
    const int n = w * 8 + ni;
    int civ = 0, oiv = 0;
    if (lane < MAXP) civ = (int)feat[(OTHER_ + lane) * 133 + n];
    if (lane >= 32 && lane < 32 + MAXP) oiv = (int)feat[(OTHER_ + MAXP + (lane - 32)) * 133 + n];
    const int L = (int)feat[95 * 133 + n];
    float acc = 0.f;
    for (int i = 0; i < L; ++i) {
      const int cv = __shfl(civ, i);
      const int ov = __shfl(oiv, 32 + i);
      acc += (lane < 32) ? ceL[cv * 32 + cl] : oeL[ov * 32 + cl];
    }
    emb[ni] = acc;
    oth[ni] = (lane < 35) ? feat[lane * 133 + n] : 0.f;
    par[ni] = (lane < 32) ? feat[(96 + lane) * 133 + n] : 0.f;
  }
  int nbr[3];
  {
    const int jA = jbase + col;
#pragma unroll
    for (int kk = 0; kk < 3; ++kk)
      nbr[kk] = (jA > 0) ? nb_s[(jA - 1) * 3 + kk] : 0;
  }
  __syncthreads();   // all feat/table reads done; region reusable

  // E3: write collate (split bf16) into sH/sL rows
#pragma unroll
  for (int ni = 0; ni < 8; ++ni) {
    const int n = w * 8 + ni;
    const int base = n * CINP;
    short h, l;
    split2(emb[ni], h, l);
    sH[base + 35 + lane] = h; sL[base + 35 + lane] = l;
    if (lane < 35) {
      split2(oth[ni], h, l);
      sH[base + lane] = h; sL[base + lane] = l;
    }
    if (lane < 32) {
      split2(par[ni], h, l);
      sH[base + 99 + lane] = h; sL[base + 99 + lane] = l;
    }
    if (lane < 29) { sH[base + 131 + lane] = 0; sL[base + 131 + lane] = 0; }
  }
  __syncthreads();

  // ================= conv1: COUT 256, SUB=8 (2 chunks of 4) =============
  f32x4 a1[8];
#pragma unroll
  for (int su = 0; su < 8; ++su) {
    a1[su][0] = 0.f; a1[su][1] = 0.f; a1[su][2] = 0.f; a1[su][3] = 0.f;
  }

#pragma unroll
  for (int kk = 0; kk < 3; ++kk) {
#pragma unroll
    for (int ks = 0; ks < 5; ++ks) {
      const int gks = kk * 5 + ks;
      const int ei = nbr[kk] * CINP + ks * 32 + grp * 8;
      const short8 ah = *reinterpret_cast<const short8*>(&sH[ei]);
      const short8 al = *reinterpret_cast<const short8*>(&sL[ei]);
#pragma unroll
      for (int sc = 0; sc < 2; ++sc) {
        short8 bh[4], bl[4];
#pragma unroll
        for (int u = 0; u < 4; ++u) {
          const int su = sc * 4 + u;
          const int wi = ((gks * 2 + wo) * 8 + su) * 64 + lane;
          bh[u] = wp1h[wi];
          bl[u] = wp1l[wi];
        }
#pragma unroll
        for (int u = 0; u < 4; ++u) {
          const int su = sc * 4 + u;
          a1[su] = __builtin_amdgcn_mfma_f32_16x16x32_bf16(ah, bh[u], a1[su], 0, 0, 0);
          a1[su] = __builtin_amdgcn_mfma_f32_16x16x32_bf16(al, bh[u], a1[su], 0, 0, 0);
          a1[su] = __builtin_amdgcn_mfma_f32_16x16x32_bf16(ah, bl[u], a1[su], 0, 0, 0);
        }
      }
    }
  }

  // ---- epilogue1: bias, zero col j=0, stats ----
  {
    double ss = 0.0, sq = 0.0;
#pragma unroll
    for (int su = 0; su < 8; ++su) {
      const float bv = b1[(wo * 8 + su) * 16 + col];
#pragma unroll
      for (int r = 0; r < 4; ++r) {
        const int j = jbase + grp * 4 + r;
        const float val = (j > 0) ? a1[su][r] + bv : 0.f;
        a1[su][r] = val;
        ss += (double)val;
        sq += (double)val * (double)val;
      }
    }
    blockStats(ss, sq, 256.0 * 128.0);
  }
  const float mean1 = bc[0], inv1 = bc[1];

  // ---- conv2 stage: all 256 ch from registers ----
#pragma unroll
  for (int su = 0; su < 8; ++su) {
    const int c = (wo * 8 + su) * 16 + col;
#pragma unroll
    for (int r = 0; r < 4; ++r) {
      const int j = jbase + grp * 4 + r;
      float v = (a1[su][r] - mean1) * inv1;
      v = fmaxf(v, 0.01f * v);
      short h, l;
      split2(v, h, l);
      sH[j * CINP + c] = h;
      sL[j * CINP + c] = l;
    }
  }
  __syncthreads();

  // ================= conv2: COUT 128, SUB=4 =================
  f32x4 a2[4];
#pragma unroll
  for (int su = 0; su < 4; ++su) {
    a2[su][0] = 0.f; a2[su][1] = 0.f; a2[su][2] = 0.f; a2[su][3] = 0.f;
  }

#pragma unroll
  for (int kk = 0; kk < 3; ++kk) {
#pragma unroll
    for (int ks = 0; ks < 8; ++ks) {
      const int gks = kk * 8 + ks;
      const int ei = nbr[kk] * CINP + ks * 32 + grp * 8;
      const short8 ah = *reinterpret_cast<const short8*>(&sH[ei]);
      const short8 al = *reinterpret_cast<const short8*>(&sL[ei]);
      short8 bh[4], bl[4];
#pragma unroll
      for (int su = 0; su < 4; ++su) {
        const int wi = ((gks * 2 + wo) * 4 + su) * 64 + lane;
        bh[su] = wp2h[wi];
        bl[su] = wp2l[wi];
      }
#pragma unroll
      for (int su = 0; su < 4; ++su) {
        a2[su] = __builtin_amdgcn_mfma_f32_16x16x32_bf16(ah, bh[su], a2[su], 0, 0, 0);
        a2[su] = __builtin_amdgcn_mfma_f32_16x16x32_bf16(al, bh[su], a2[su], 0, 0, 0);
        a2[su] = __builtin_amdgcn_mfma_f32_16x16x32_bf16(ah, bl[su], a2[su], 0, 0, 0);
      }
    }
  }

  // ---- epilogue2 ----
  {
    double ss = 0.0, sq = 0.0;
#pragma unroll
    for (int su = 0; su < 4; ++su) {
      const float bv = b2[(wo * 4 + su) * 16 + col];
#pragma unroll
      for (int r = 0; r < 4; ++r) {
        const int j = jbase + grp * 4 + r;
        const float val = (j > 0) ? a2[su][r] + bv : 0.f;
        a2[su][r] = val;
        ss += (double)val;
        sq += (double)val * (double)val;
      }
    }
    blockStats(ss, sq, 128.0 * 128.0);
  }
  const float mean2 = bc[0], inv2 = bc[1];

  // ---- conv3 stage: all 128 ch ----
#pragma unroll
  for (int su = 0; su < 4; ++su) {
    const int c = (wo * 4 + su) * 16 + col;
#pragma unroll
    for (int r = 0; r < 4; ++r) {
      const int j = jbase + grp * 4 + r;
      float v = (a2[su][r] - mean2) * inv2;
      v = fmaxf(v, 0.01f * v);
      short h, l;
      split2(v, h, l);
      sH[j * CINP + c] = h;
      sL[j * CINP + c] = l;
    }
  }
  __syncthreads();

  // ================= conv3: COUT 64, SUB=2 =================
  f32x4 a3[2];
#pragma unroll
  for (int su = 0; su < 2; ++su) {
    a3[su][0] = 0.f; a3[su][1] = 0.f; a3[su][2] = 0.f; a3[su][3] = 0.f;
  }

#pragma unroll
  for (int kk = 0; kk < 3; ++kk) {
#pragma unroll
    for (int ks = 0; ks < 4; ++ks) {
      const int gks = kk * 4 + ks;
      const int ei = nbr[kk] * CINP + ks * 32 + grp * 8;
      const short8 ah = *reinterpret_cast<const short8*>(&sH[ei]);
      const short8 al = *reinterpret_cast<const short8*>(&sL[ei]);
      short8 bh[2], bl[2];
#pragma unroll
      for (int su = 0; su < 2; ++su) {
        const int wi = ((gks * 2 + wo) * 2 + su) * 64 + lane;
        bh[su] = wp3h[wi];
        bl[su] = wp3l[wi];
      }
#pragma unroll
      for (int su = 0; su < 2; ++su) {
        a3[su] = __builtin_amdgcn_mfma_f32_16x16x32_bf16(ah, bh[su], a3[su], 0, 0, 0);
        a3[su] = __builtin_amdgcn_mfma_f32_16x16x32_bf16(al, bh[su], a3[su], 0, 0, 0);
        a3[su] = __builtin_amdgcn_mfma_f32_16x16x32_bf16(ah, bl[su], a3[su], 0, 0, 0);
      }
    }
  }

  // ---- epilogue3 + stats ----
  {
    double ss = 0.0, sq = 0.0;
#pragma unroll
    for (int su = 0; su < 2; ++su) {
      const float bv = b3[(wo * 2 + su) * 16 + col];
#pragma unroll
      for (int r = 0; r < 4; ++r) {
        const int j = jbase + grp * 4 + r;
        const float val = (j > 0) ? a3[su][r] + bv : 0.f;
        a3[su][r] = val;
        ss += (double)val;
        sq += (double)val * (double)val;
      }
    }
    blockStats(ss, sq, 64.0 * 128.0);
  }
  const float mean3 = bc[0], inv3 = bc[1];

  // ---- maxpool over this wave's 16 j-rows, then cross-wj in LDS ----
#pragma unroll
  for (int su = 0; su < 2; ++su) {
    float pm = -3.4e38f;
#pragma unroll
    for (int r = 0; r < 4; ++r)
      pm = fmaxf(pm, (a3[su][r] - mean3) * inv3);
    pm = fmaxf(pm, __shfl_xor(pm, 16, 64));
    pm = fmaxf(pm, __shfl_xor(pm, 32, 64));
    if (lane < 16) poolw[w][su * 16 + col] = pm;
  }
  __syncthreads();

  // ---- 2-layer MLP (wave 0). channel c owned by waves wj*2 + (c>>5). ----
  if (w == 0) {
    float hval = 0.f;
    if (lane < 32) {
      float a = fb1[lane];
#pragma unroll 8
      for (int c = 0; c < 64; ++c) {
        const int half = c >> 5, loc = c & 31;
        float p = poolw[half][loc];
#pragma unroll
        for (int jw = 1; jw < 8; ++jw) p = fmaxf(p, poolw[jw * 2 + half][loc]);
        a = fmaf(p, fw1[lane * 64 + c], a);
      }
      hval = fmaxf(a, 0.f) * fw2[lane];
    }
#pragma unroll
    for (int o = 32; o > 0; o >>= 1) hval += __shfl_down(hval, o, 64);
    if (lane == 0) out[b] = hval + fb2[0];
  }
}

// ---------------------------------------------------------------------------
extern "C" void kernel_launch(void* const* d_in, const int* in_sizes, int n_in,
                              void* d_out, int out_size, void* d_ws, size_t ws_size,
                              hipStream_t stream) {
  const float* feature   = (const float*)d_in[0];
  const void*  indexes   = d_in[1];
  const float* col_embed = (const float*)d_in[2];
  const float* op_embed  = (const float*)d_in[3];
  const float* w1  = (const float*)d_in[4];
  const float* b1  = (const float*)d_in[5];
  const float* w2  = (const float*)d_in[6];
  const float* b2  = (const float*)d_in[7];
  const float* w3  = (const float*)d_in[8];
  const float* b3  = (const float*)d_in[9];
  const float* fw1 = (const float*)d_in[10];
  const float* fb1 = (const float*)d_in[11];
  const float* fw2 = (const float*)d_in[12];
  const float* fb2 = (const float*)d_in[13];
  float* out = (float*)d_out;

  char* ws = (char*)d_ws;
  size_t off = 0;
  auto carve = [&](size_t bytes) -> char* {
    off = (off + 255) & ~(size_t)255;
    char* p = ws + off;
    off += bytes;
    return p;
  };
  int*   idx32 = (int*)carve((size_t)S_IDX * sizeof(int));
  short* w1h   = (short*)carve((size_t)S_P1 * sizeof(short));
  short* w1l   = (short*)carve((size_t)S_P1 * sizeof(short));
  short* w2h   = (short*)carve((size_t)S_P2 * sizeof(short));
  short* w2l   = (short*)carve((size_t)S_P2 * sizeof(short));
  short* w3h   = (short*)carve((size_t)S_P3 * sizeof(short));
  short* w3l   = (short*)carve((size_t)S_P3 * sizeof(short));
  (void)ws_size; (void)in_sizes; (void)n_in; (void)out_size;

  hipLaunchKernelGGL(prep_kernel, dim3(PREP_BLOCKS), dim3(512), 0, stream,
                     indexes, idx32, w1, w1h, w1l, w2, w2h, w2l, w3, w3h, w3l);
  hipLaunchKernelGGL(fused_kernel, dim3(B_), dim3(1024), 0, stream,
                     feature, col_embed, op_embed, idx32,
                     w1h, w1l, w2h, w2l, w3h, w3l,
                     b1, b2, b3, fw1, fb1, fw2, fb2, out);
}

// Round 19
// 83.715 us; speedup vs baseline: 1.2442x; 1.2442x over previous
//
#include <hip/hip_runtime.h>
#include <hip/hip_bf16.h>
#include <math.h>

// Problem constants (B, N, D) = (256, 128, 128)
#define B_    256
#define N_    128
#define MAXP  30
#define OTHER_ 35
#define CIN1  131
#define NIDX  381

#define KPAD1 160
#define KPAD2 256
#define KPAD3 128
#define S_IDX (B_ * NIDX)          // 97536
#define S_P1  (15 * 4 * 4 * 512)   // 122880  (gks * NWO4 * SUB4 * 512)
#define S_P2  (24 * 4 * 2 * 512)   // 98304
#define S_P3  (12 * 4 * 1 * 512)   // 24576
#define PREP_TOTAL (S_IDX + S_P1 + S_P2 + S_P3)
#define PREP_BLOCKS ((PREP_TOTAL + 511) / 512)

typedef short short8 __attribute__((ext_vector_type(8)));
typedef float f32x4 __attribute__((ext_vector_type(4)));

// RNE split of f32 into hi/lo bf16 via bit math (prep only)
__device__ inline void split1(float v, short& h, short& l) {
  unsigned u = __float_as_uint(v);
  unsigned hb = (u + 0x7fffu + ((u >> 16) & 1u)) >> 16;
  float fh = __uint_as_float(hb << 16);
  float r = v - fh;
  unsigned u2 = __float_as_uint(r);
  unsigned lb = (u2 + 0x7fffu + ((u2 >> 16) & 1u)) >> 16;
  h = (short)hb;
  l = (short)lb;
}

// RNE split via HW cvt — hot path
__device__ inline void split2(float v, short& h, short& l) {
  __hip_bfloat16 hb = __float2bfloat16(v);
  float fh = __bfloat162float(hb);
  __hip_bfloat16 lb = __float2bfloat16(v - fh);
  __builtin_memcpy(&h, &hb, 2);
  __builtin_memcpy(&l, &lb, 2);
}

// ---------------------------------------------------------------------------
// Weight pack: l -> [gks][g][su][lane][e]; g in [0,NWO). Value w[oc][ch][kk],
// oc=(g*SUB+su)*16+(lane&15), ctot=gks*32+((lane>>4)&3)*8+e,
// kk=ctot/KPAD, ch=ctot%KPAD (0 if ch>=KREAL).
// ---------------------------------------------------------------------------
template <int KREAL, int KPAD, int SUB, int NWO>
__device__ inline void packw(int l, const float* __restrict__ w,
                             short* __restrict__ oh, short* __restrict__ ol) {
  const int e = l & 7;
  const int lane = (l >> 3) & 63;
  const int x = l >> 9;
  const int su = x % SUB;
  const int y = x / SUB;
  const int g = y % NWO;
  const int gks = y / NWO;
  const int oc = (g * SUB + su) * 16 + (lane & 15);
  const int ctot = gks * 32 + ((lane >> 4) & 3) * 8 + e;
  const int kk = ctot / KPAD;
  const int ch = ctot - kk * KPAD;
  const float v = (ch < KREAL) ? w[(oc * KREAL + ch) * 3 + kk] : 0.f;
  short h, lo;
  split1(v, h, lo);
  oh[l] = h;
  ol[l] = lo;
}

// ---------------------------------------------------------------------------
// Prep: idx convert (wave-uniform int64 detection) + weight packing only.
// ---------------------------------------------------------------------------
__global__ __launch_bounds__(512) void prep_kernel(
    const void* __restrict__ rawIdx, int* __restrict__ idx32,
    const float* __restrict__ w1, short* __restrict__ w1h, short* __restrict__ w1l,
    const float* __restrict__ w2, short* __restrict__ w2h, short* __restrict__ w2l,
    const float* __restrict__ w3, short* __restrict__ w3h, short* __restrict__ w3l) {
  const int gid = blockIdx.x * 512 + threadIdx.x;
  if (gid < S_IDX) {
    // int64 LE view is (v,0,v,0,...) with v in [0,128)
    const int* r32 = (const int*)rawIdx;
    const int lane = threadIdx.x & 63;
    const int lo = r32[2 * lane];
    const int hi = r32[2 * lane + 1];
    const bool ok = (hi == 0 && lo >= 0 && lo < N_);
    const bool is64 = __all(ok);
    idx32[gid] = is64 ? (int)((const long long*)rawIdx)[gid] : ((const int*)rawIdx)[gid];
  } else if (gid < S_IDX + S_P1) {
    packw<131, KPAD1, 4, 4>(gid - S_IDX, w1, w1h, w1l);
  } else if (gid < S_IDX + S_P1 + S_P2) {
    packw<256, KPAD2, 2, 4>(gid - (S_IDX + S_P1), w2, w2h, w2l);
  } else if (gid < PREP_TOTAL) {
    packw<128, KPAD3, 1, 4>(gid - (S_IDX + S_P1 + S_P2), w3, w3h, w3l);
  }
}

// ---------------------------------------------------------------------------
// FUSED v8 = r17 (best, 79.5us) + (a) single-barrier blockStats computed
// redundantly by all threads (removes 3 barriers + tid0 serialization),
// (b) embed gather with 8-node interleaved ILP (8 independent LDS chains).
// Wave grid (wj 0..3 x wo 0..3), JT=2, oc-quarters. Block = one batch.
// ---------------------------------------------------------------------------
__global__ __launch_bounds__(1024, 1) void fused_kernel(
    const float* __restrict__ feature,
    const float* __restrict__ col_embed,   // (200,32)
    const float* __restrict__ op_embed,    // (20,32)
    const int* __restrict__ idx,
    const short* __restrict__ w1h, const short* __restrict__ w1l,
    const short* __restrict__ w2h, const short* __restrict__ w2l,
    const short* __restrict__ w3h, const short* __restrict__ w3l,
    const float* __restrict__ b1, const float* __restrict__ b2,
    const float* __restrict__ b3,
    const float* __restrict__ fw1, const float* __restrict__ fb1,
    const float* __restrict__ fw2, const float* __restrict__ fb2,
    float* __restrict__ out) {
  constexpr int CINP = 264;   // shorts per row (528 B)

  __shared__ short smem[128 * CINP * 2];   // sH | sL, 135.2 KB
  __shared__ int nb_s[NIDX];
  __shared__ double red[32];
  __shared__ float poolw[16][16];

  short* sH = smem;
  short* sL = smem + 128 * CINP;
  float* feat = (float*)smem;                 // [128][133], aliased
  float* ceL  = ((float*)smem) + 128 * 133;   // 200x32, aliased
  float* oeL  = ceL + 200 * 32;               // 20x32

  const int b = blockIdx.x;
  const int tid = threadIdx.x;
  const int lane = tid & 63;
  const int w = tid >> 6;       // 0..15
  const int wj = w >> 2;        // 0..3
  const int wo = w & 3;         // 0..3
  const int col = lane & 15;
  const int grp = (lane >> 4) & 3;
  const int jbase = wj * 32;
  const int cl = lane & 31;

  const short8* __restrict__ wp1h = (const short8*)w1h;
  const short8* __restrict__ wp1l = (const short8*)w1l;
  const short8* __restrict__ wp2h = (const short8*)w2h;
  const short8* __restrict__ wp2l = (const short8*)w2l;
  const short8* __restrict__ wp3h = (const short8*)w3h;
  const short8* __restrict__ wp3l = (const short8*)w3l;

  // one barrier; every thread computes mean/inv redundantly from partials
  auto blockStats = [&](double ss, double sq, double cnt, float& mean, float& inv) {
#pragma unroll
    for (int o = 32; o > 0; o >>= 1) {
      ss += __shfl_down(ss, o, 64);
      sq += __shfl_down(sq, o, 64);
    }
    if (lane == 0) { red[w * 2] = ss; red[w * 2 + 1] = sq; }
    __syncthreads();
    double S = 0.0, Q = 0.0;
#pragma unroll
    for (int i = 0; i < 16; ++i) { S += red[i * 2]; Q += red[i * 2 + 1]; }
    const double m = S / cnt;
    double var = (Q - S * S / cnt) / (cnt - 1.0);
    if (var < 0.0) var = 0.0;
    mean = (float)m;
    inv = (float)(1.0 / (sqrt(var) + 1e-5));
  };

  // ================= PHASE E: embed =================
  {
    const float* fb = feature + (size_t)b * 16384;
#pragma unroll
    for (int it = 0; it < 4; ++it) {
      const int t = it * 1024 + tid;
      const int d = t >> 5;
      const int c4 = (t & 31) * 4;
      const float4 v = *reinterpret_cast<const float4*>(&fb[d * 128 + c4]);
      float* p = &feat[d * 133 + c4];
      p[0] = v.x; p[1] = v.y; p[2] = v.z; p[3] = v.w;
    }
    const float4* s = (const float4*)col_embed;
    float4* d4 = (float4*)ceL;
#pragma unroll
    for (int it = 0; it < 2; ++it) {
      const int t = it * 1024 + tid;
      if (t < 1600) d4[t] = s[t];
    }
    if (tid < 160) ((float4*)oeL)[tid] = ((const float4*)op_embed)[tid];
    if (tid < NIDX) nb_s[tid] = idx[b * NIDX + tid];
  }
  __syncthreads();

  // E2: 8 nodes per wave, interleaved i-loop (8 independent chains)
  float emb[8], oth[8], par[8];
  int civ8[8], oiv8[8], L8[8];
  int Lmax = 0;
#pragma unroll
  for (int ni = 0; ni < 8; ++ni) {
    const int n = w * 8 + ni;
    civ8[ni] = (lane < MAXP) ? (int)feat[(OTHER_ + lane) * 133 + n] : 0;
    oiv8[ni] = (lane >= 32 && lane < 32 + MAXP)
                   ? (int)feat[(OTHER_ + MAXP + (lane - 32)) * 133 + n] : 0;
    L8[ni] = (int)feat[95 * 133 + n];   // uniform across lanes
    Lmax = (L8[ni] > Lmax) ? L8[ni] : Lmax;
    emb[ni] = 0.f;
    oth[ni] = (lane < 35) ? feat[lane * 133 + n] : 0.f;
    par[ni] = (lane < 32) ? feat[(96 + lane) * 133 + n] : 0.f;
  }
  for (int i = 0; i < Lmax; ++i) {
#pragma unroll
    for (int ni = 0; ni < 8; ++ni) {
      if (i < L8[ni]) {
        const int cv = __shfl(civ8[ni], i);
        const int ov = __shfl(oiv8[ni], 32 + i);
        emb[ni] += (lane < 32) ? ceL[cv * 32 + cl] : oeL[ov * 32 + cl];
      }
    }
  }
  int nbr[2][3];
#pragma unroll
  for (int jt = 0; jt < 2; ++jt) {
    const int jA = jbase + jt * 16 + col;
#pragma unroll
    for (int kk = 0; kk < 3; ++kk)
      nbr[jt][kk] = (jA > 0) ? nb_s[(jA - 1) * 3 + kk] : 0;
  }
  __syncthreads();   // all feat/table reads done; region reusable

  // E3: write collate (split bf16) into sH/sL rows
#pragma unroll
  for (int ni = 0; ni < 8; ++ni) {
    const int n = w * 8 + ni;
    const int base = n * CINP;
    short h, l;
    split2(emb[ni], h, l);
    sH[base + 35 + lane] = h; sL[base + 35 + lane] = l;
    if (lane < 35) {
      split2(oth[ni], h, l);
      sH[base + lane] = h; sL[base + lane] = l;
    }
    if (lane < 32) {
      split2(par[ni], h, l);
      sH[base + 99 + lane] = h; sL[base + 99 + lane] = l;
    }
    if (lane < 29) { sH[base + 131 + lane] = 0; sL[base + 131 + lane] = 0; }
  }
  __syncthreads();

  // ================= conv1: COUT 256, SUB=4 =================
  f32x4 a1[2][4];
#pragma unroll
  for (int jt = 0; jt < 2; ++jt)
#pragma unroll
    for (int su = 0; su < 4; ++su) {
      a1[jt][su][0] = 0.f; a1[jt][su][1] = 0.f;
      a1[jt][su][2] = 0.f; a1[jt][su][3] = 0.f;
    }

#pragma unroll
  for (int kk = 0; kk < 3; ++kk) {
#pragma unroll
    for (int ks = 0; ks < 5; ++ks) {
      const int gks = kk * 5 + ks;
      short8 ah[2], al[2];
#pragma unroll
      for (int jt = 0; jt < 2; ++jt) {
        const int ei = nbr[jt][kk] * CINP + ks * 32 + grp * 8;
        ah[jt] = *reinterpret_cast<const short8*>(&sH[ei]);
        al[jt] = *reinterpret_cast<const short8*>(&sL[ei]);
      }
      short8 bh[4], bl[4];
#pragma unroll
      for (int su = 0; su < 4; ++su) {
        const int wi = ((gks * 4 + wo) * 4 + su) * 64 + lane;
        bh[su] = wp1h[wi];
        bl[su] = wp1l[wi];
      }
#pragma unroll
      for (int jt = 0; jt < 2; ++jt)
#pragma unroll
        for (int su = 0; su < 4; ++su) {
          a1[jt][su] = __builtin_amdgcn_mfma_f32_16x16x32_bf16(ah[jt], bh[su], a1[jt][su], 0, 0, 0);
          a1[jt][su] = __builtin_amdgcn_mfma_f32_16x16x32_bf16(al[jt], bh[su], a1[jt][su], 0, 0, 0);
          a1[jt][su] = __builtin_amdgcn_mfma_f32_16x16x32_bf16(ah[jt], bl[su], a1[jt][su], 0, 0, 0);
        }
    }
  }

  // ---- epilogue1: bias, zero col j=0, stats ----
  float mean1, inv1;
  {
    double ss = 0.0, sq = 0.0;
#pragma unroll
    for (int su = 0; su < 4; ++su) {
      const float bv = b1[(wo * 4 + su) * 16 + col];
#pragma unroll
      for (int jt = 0; jt < 2; ++jt)
#pragma unroll
        for (int r = 0; r < 4; ++r) {
          const int j = jbase + jt * 16 + grp * 4 + r;
          const float val = (j > 0) ? a1[jt][su][r] + bv : 0.f;
          a1[jt][su][r] = val;
          ss += (double)val;
          sq += (double)val * (double)val;
        }
    }
    blockStats(ss, sq, 256.0 * 128.0, mean1, inv1);
  }
  __syncthreads();   // red consumed; also orders next LDS writes

  // ---- conv2 stage: all 256 ch from registers ----
#pragma unroll
  for (int su = 0; su < 4; ++su) {
    const int c = (wo * 4 + su) * 16 + col;
#pragma unroll
    for (int jt = 0; jt < 2; ++jt)
#pragma unroll
      for (int r = 0; r < 4; ++r) {
        const int j = jbase + jt * 16 + grp * 4 + r;
        float v = (a1[jt][su][r] - mean1) * inv1;
        v = fmaxf(v, 0.01f * v);
        short h, l;
        split2(v, h, l);
        sH[j * CINP + c] = h;
        sL[j * CINP + c] = l;
      }
  }
  __syncthreads();

  // ================= conv2: COUT 128, SUB=2 =================
  f32x4 a2[2][2];
#pragma unroll
  for (int jt = 0; jt < 2; ++jt)
#pragma unroll
    for (int su = 0; su < 2; ++su) {
      a2[jt][su][0] = 0.f; a2[jt][su][1] = 0.f;
      a2[jt][su][2] = 0.f; a2[jt][su][3] = 0.f;
    }

#pragma unroll
  for (int kk = 0; kk < 3; ++kk) {
#pragma unroll
    for (int ks = 0; ks < 8; ++ks) {
      const int gks = kk * 8 + ks;
      short8 ah[2], al[2];
#pragma unroll
      for (int jt = 0; jt < 2; ++jt) {
        const int ei = nbr[jt][kk] * CINP + ks * 32 + grp * 8;
        ah[jt] = *reinterpret_cast<const short8*>(&sH[ei]);
        al[jt] = *reinterpret_cast<const short8*>(&sL[ei]);
      }
      short8 bh[2], bl[2];
#pragma unroll
      for (int su = 0; su < 2; ++su) {
        const int wi = ((gks * 4 + wo) * 2 + su) * 64 + lane;
        bh[su] = wp2h[wi];
        bl[su] = wp2l[wi];
      }
#pragma unroll
      for (int jt = 0; jt < 2; ++jt)
#pragma unroll
        for (int su = 0; su < 2; ++su) {
          a2[jt][su] = __builtin_amdgcn_mfma_f32_16x16x32_bf16(ah[jt], bh[su], a2[jt][su], 0, 0, 0);
          a2[jt][su] = __builtin_amdgcn_mfma_f32_16x16x32_bf16(al[jt], bh[su], a2[jt][su], 0, 0, 0);
          a2[jt][su] = __builtin_amdgcn_mfma_f32_16x16x32_bf16(ah[jt], bl[su], a2[jt][su], 0, 0, 0);
        }
    }
  }

  // ---- epilogue2 ----
  float mean2, inv2;
  {
    double ss = 0.0, sq = 0.0;
#pragma unroll
    for (int su = 0; su < 2; ++su) {
      const float bv = b2[(wo * 2 + su) * 16 + col];
#pragma unroll
      for (int jt = 0; jt < 2; ++jt)
#pragma unroll
        for (int r = 0; r < 4; ++r) {
          const int j = jbase + jt * 16 + grp * 4 + r;
          const float val = (j > 0) ? a2[jt][su][r] + bv : 0.f;
          a2[jt][su][r] = val;
          ss += (double)val;
          sq += (double)val * (double)val;
        }
    }
    blockStats(ss, sq, 128.0 * 128.0, mean2, inv2);
  }
  __syncthreads();

  // ---- conv3 stage: all 128 ch ----
#pragma unroll
  for (int su = 0; su < 2; ++su) {
    const int c = (wo * 2 + su) * 16 + col;
#pragma unroll
    for (int jt = 0; jt < 2; ++jt)
#pragma unroll
      for (int r = 0; r < 4; ++r) {
        const int j = jbase + jt * 16 + grp * 4 + r;
        float v = (a2[jt][su][r] - mean2) * inv2;
        v = fmaxf(v, 0.01f * v);
        short h, l;
        split2(v, h, l);
        sH[j * CINP + c] = h;
        sL[j * CINP + c] = l;
      }
  }
  __syncthreads();

  // ================= conv3: COUT 64, SUB=1 =================
  f32x4 a3[2];
#pragma unroll
  for (int jt = 0; jt < 2; ++jt) {
    a3[jt][0] = 0.f; a3[jt][1] = 0.f; a3[jt][2] = 0.f; a3[jt][3] = 0.f;
  }

#pragma unroll
  for (int kk = 0; kk < 3; ++kk) {
#pragma unroll
    for (int ks = 0; ks < 4; ++ks) {
      const int gks = kk * 4 + ks;
      short8 ah[2], al[2];
#pragma unroll
      for (int jt = 0; jt < 2; ++jt) {
        const int ei = nbr[jt][kk] * CINP + ks * 32 + grp * 8;
        ah[jt] = *reinterpret_cast<const short8*>(&sH[ei]);
        al[jt] = *reinterpret_cast<const short8*>(&sL[ei]);
      }
      short8 bh, bl;
      {
        const int wi = (gks * 4 + wo) * 64 + lane;
        bh = wp3h[wi];
        bl = wp3l[wi];
      }
#pragma unroll
      for (int jt = 0; jt < 2; ++jt) {
        a3[jt] = __builtin_amdgcn_mfma_f32_16x16x32_bf16(ah[jt], bh, a3[jt], 0, 0, 0);
        a3[jt] = __builtin_amdgcn_mfma_f32_16x16x32_bf16(al[jt], bh, a3[jt], 0, 0, 0);
        a3[jt] = __builtin_amdgcn_mfma_f32_16x16x32_bf16(ah[jt], bl, a3[jt], 0, 0, 0);
      }
    }
  }

  // ---- epilogue3 + stats ----
  float mean3, inv3;
  {
    double ss = 0.0, sq = 0.0;
    const float bv = b3[wo * 16 + col];
#pragma unroll
    for (int jt = 0; jt < 2; ++jt)
#pragma unroll
      for (int r = 0; r < 4; ++r) {
        const int j = jbase + jt * 16 + grp * 4 + r;
        const float val = (j > 0) ? a3[jt][r] + bv : 0.f;
        a3[jt][r] = val;
        ss += (double)val;
        sq += (double)val * (double)val;
      }
    blockStats(ss, sq, 64.0 * 128.0, mean3, inv3);
  }

  // ---- maxpool over this wave's j-range, then cross-wj in LDS ----
  {
    float pm = -3.4e38f;
#pragma unroll
    for (int jt = 0; jt < 2; ++jt)
#pragma unroll
      for (int r = 0; r < 4; ++r)
        pm = fmaxf(pm, (a3[jt][r] - mean3) * inv3);
    pm = fmaxf(pm, __shfl_xor(pm, 16, 64));
    pm = fmaxf(pm, __shfl_xor(pm, 32, 64));
    if (lane < 16) poolw[w][col] = pm;
  }
  __syncthreads();

  // ---- 2-layer MLP (wave 0) ----
  if (w == 0) {
    float hval = 0.f;
    if (lane < 32) {
      float a = fb1[lane];
#pragma unroll 8
      for (int c = 0; c < 64; ++c) {
        const int oq = c >> 4, oc16 = c & 15;
        float p = poolw[oq][oc16];
#pragma unroll
        for (int jw = 1; jw < 4; ++jw) p = fmaxf(p, poolw[jw * 4 + oq][oc16]);
        a = fmaf(p, fw1[lane * 64 + c], a);
      }
      hval = fmaxf(a, 0.f) * fw2[lane];
    }
#pragma unroll
    for (int o = 32; o > 0; o >>= 1) hval += __shfl_down(hval, o, 64);
    if (lane == 0) out[b] = hval + fb2[0];
  }
}

// ---------------------------------------------------------------------------
extern "C" void kernel_launch(void* const* d_in, const int* in_sizes, int n_in,
                              void* d_out, int out_size, void* d_ws, size_t ws_size,
                              hipStream_t stream) {
  const float* feature   = (const float*)d_in[0];
  const void*  indexes   = d_in[1];
  const float* col_embed = (const float*)d_in[2];
  const float* op_embed  = (const float*)d_in[3];
  const float* w1  = (const float*)d_in[4];
  const float* b1  = (const float*)d_in[5];
  const float* w2  = (const float*)d_in[6];
  const float* b2  = (const float*)d_in[7];
  const float* w3  = (const float*)d_in[8];
  const float* b3  = (const float*)d_in[9];
  const float* fw1 = (const float*)d_in[10];
  const float* fb1 = (const float*)d_in[11];
  const float* fw2 = (const float*)d_in[12];
  const float* fb2 = (const float*)d_in[13];
  float* out = (float*)d_out;

  char* ws = (char*)d_ws;
  size_t off = 0;
  auto carve = [&](size_t bytes) -> char* {
    off = (off + 255) & ~(size_t)255;
    char* p = ws + off;
    off += bytes;
    return p;
  };
  int*   idx32 = (int*)carve((size_t)S_IDX * sizeof(int));
  short* w1h   = (short*)carve((size_t)S_P1 * sizeof(short));
  short* w1l   = (short*)carve((size_t)S_P1 * sizeof(short));
  short* w2h   = (short*)carve((size_t)S_P2 * sizeof(short));
  short* w2l   = (short*)carve((size_t)S_P2 * sizeof(short));
  short* w3h   = (short*)carve((size_t)S_P3 * sizeof(short));
  short* w3l   = (short*)carve((size_t)S_P3 * sizeof(short));
  (void)ws_size; (void)in_sizes; (void)n_in; (void)out_size;

  hipLaunchKernelGGL(prep_kernel, dim3(PREP_BLOCKS), dim3(512), 0, stream,
                     indexes, idx32, w1, w1h, w1l, w2, w2h, w2l, w3, w3h, w3l);
  hipLaunchKernelGGL(fused_kernel, dim3(B_), dim3(1024), 0, stream,
                     feature, col_embed, op_embed, idx32,
                     w1h, w1l, w2h, w2l, w3h, w3l,
                     b1, b2, b3, fw1, fb1, fw2, fb2, out);
}

// Round 20
// 79.364 us; speedup vs baseline: 1.3124x; 1.0548x over previous
//
#include <hip/hip_runtime.h>
#include <hip/hip_bf16.h>
#include <math.h>

// Problem constants (B, N, D) = (256, 128, 128)
#define B_    256
#define N_    128
#define MAXP  30
#define OTHER_ 35
#define CIN1  131
#define NIDX  381

#define KPAD1 160
#define KPAD2 256
#define KPAD3 128
#define S_IDX (B_ * NIDX)          // 97536
#define S_P1  (15 * 4 * 4 * 512)   // 122880  (gks * NWO4 * SUB4 * 512)
#define S_P2  (24 * 4 * 2 * 512)   // 98304
#define S_P3  (12 * 4 * 1 * 512)   // 24576
#define PREP_TOTAL (S_IDX + S_P1 + S_P2 + S_P3)
#define PREP_BLOCKS ((PREP_TOTAL + 511) / 512)

typedef short short8 __attribute__((ext_vector_type(8)));
typedef float f32x4 __attribute__((ext_vector_type(4)));

// RNE split of f32 into hi/lo bf16 via bit math (prep only)
__device__ inline void split1(float v, short& h, short& l) {
  unsigned u = __float_as_uint(v);
  unsigned hb = (u + 0x7fffu + ((u >> 16) & 1u)) >> 16;
  float fh = __uint_as_float(hb << 16);
  float r = v - fh;
  unsigned u2 = __float_as_uint(r);
  unsigned lb = (u2 + 0x7fffu + ((u2 >> 16) & 1u)) >> 16;
  h = (short)hb;
  l = (short)lb;
}

// RNE split via HW cvt — hot path
__device__ inline void split2(float v, short& h, short& l) {
  __hip_bfloat16 hb = __float2bfloat16(v);
  float fh = __bfloat162float(hb);
  __hip_bfloat16 lb = __float2bfloat16(v - fh);
  __builtin_memcpy(&h, &hb, 2);
  __builtin_memcpy(&l, &lb, 2);
}

// ---------------------------------------------------------------------------
// Weight pack: l -> [gks][g][su][lane][e]; g in [0,NWO). Value w[oc][ch][kk],
// oc=(g*SUB+su)*16+(lane&15), ctot=gks*32+((lane>>4)&3)*8+e,
// kk=ctot/KPAD, ch=ctot%KPAD (0 if ch>=KREAL).
// ---------------------------------------------------------------------------
template <int KREAL, int KPAD, int SUB, int NWO>
__device__ inline void packw(int l, const float* __restrict__ w,
                             short* __restrict__ oh, short* __restrict__ ol) {
  const int e = l & 7;
  const int lane = (l >> 3) & 63;
  const int x = l >> 9;
  const int su = x % SUB;
  const int y = x / SUB;
  const int g = y % NWO;
  const int gks = y / NWO;
  const int oc = (g * SUB + su) * 16 + (lane & 15);
  const int ctot = gks * 32 + ((lane >> 4) & 3) * 8 + e;
  const int kk = ctot / KPAD;
  const int ch = ctot - kk * KPAD;
  const float v = (ch < KREAL) ? w[(oc * KREAL + ch) * 3 + kk] : 0.f;
  short h, lo;
  split1(v, h, lo);
  oh[l] = h;
  ol[l] = lo;
}

// ---------------------------------------------------------------------------
// Prep: idx convert (wave-uniform int64 detection) + weight packing only.
// ---------------------------------------------------------------------------
__global__ __launch_bounds__(512) void prep_kernel(
    const void* __restrict__ rawIdx, int* __restrict__ idx32,
    const float* __restrict__ w1, short* __restrict__ w1h, short* __restrict__ w1l,
    const float* __restrict__ w2, short* __restrict__ w2h, short* __restrict__ w2l,
    const float* __restrict__ w3, short* __restrict__ w3h, short* __restrict__ w3l) {
  const int gid = blockIdx.x * 512 + threadIdx.x;
  if (gid < S_IDX) {
    // int64 LE view is (v,0,v,0,...) with v in [0,128)
    const int* r32 = (const int*)rawIdx;
    const int lane = threadIdx.x & 63;
    const int lo = r32[2 * lane];
    const int hi = r32[2 * lane + 1];
    const bool ok = (hi == 0 && lo >= 0 && lo < N_);
    const bool is64 = __all(ok);
    idx32[gid] = is64 ? (int)((const long long*)rawIdx)[gid] : ((const int*)rawIdx)[gid];
  } else if (gid < S_IDX + S_P1) {
    packw<131, KPAD1, 4, 4>(gid - S_IDX, w1, w1h, w1l);
  } else if (gid < S_IDX + S_P1 + S_P2) {
    packw<256, KPAD2, 2, 4>(gid - (S_IDX + S_P1), w2, w2h, w2l);
  } else if (gid < PREP_TOTAL) {
    packw<128, KPAD3, 1, 4>(gid - (S_IDX + S_P1 + S_P2), w3, w3h, w3l);
  }
}

// ---------------------------------------------------------------------------
// FUSED v6 (r17 = session best, restored verbatim): embed in-kernel,
// 16 waves (wj 0..3 x wo 0..3), JT=2, oc-quarters, full-layer LDS staging,
// tid0-computed stats. Only global write: out[b].
// ---------------------------------------------------------------------------
__global__ __launch_bounds__(1024, 1) void fused_kernel(
    const float* __restrict__ feature,
    const float* __restrict__ col_embed,   // (200,32)
    const float* __restrict__ op_embed,    // (20,32)
    const int* __restrict__ idx,
    const short* __restrict__ w1h, const short* __restrict__ w1l,
    const short* __restrict__ w2h, const short* __restrict__ w2l,
    const short* __restrict__ w3h, const short* __restrict__ w3l,
    const float* __restrict__ b1, const float* __restrict__ b2,
    const float* __restrict__ b3,
    const float* __restrict__ fw1, const float* __restrict__ fb1,
    const float* __restrict__ fw2, const float* __restrict__ fb2,
    float* __restrict__ out) {
  constexpr int CINP = 264;   // shorts per row (528 B)

  __shared__ short smem[128 * CINP * 2];   // sH | sL, 135.2 KB
  __shared__ int nb_s[NIDX];
  __shared__ double red[32];
  __shared__ float bc[2];
  __shared__ float poolw[16][16];

  short* sH = smem;
  short* sL = smem + 128 * CINP;
  float* feat = (float*)smem;                 // [128][133], aliased
  float* ceL  = ((float*)smem) + 128 * 133;   // 200x32, aliased
  float* oeL  = ceL + 200 * 32;               // 20x32

  const int b = blockIdx.x;
  const int tid = threadIdx.x;
  const int lane = tid & 63;
  const int w = tid >> 6;       // 0..15
  const int wj = w >> 2;        // 0..3
  const int wo = w & 3;         // 0..3
  const int col = lane & 15;
  const int grp = (lane >> 4) & 3;
  const int jbase = wj * 32;
  const int cl = lane & 31;

  const short8* __restrict__ wp1h = (const short8*)w1h;
  const short8* __restrict__ wp1l = (const short8*)w1l;
  const short8* __restrict__ wp2h = (const short8*)w2h;
  const short8* __restrict__ wp2l = (const short8*)w2l;
  const short8* __restrict__ wp3h = (const short8*)w3h;
  const short8* __restrict__ wp3l = (const short8*)w3l;

  auto blockStats = [&](double ss, double sq, double cnt) {
#pragma unroll
    for (int o = 32; o > 0; o >>= 1) {
      ss += __shfl_down(ss, o, 64);
      sq += __shfl_down(sq, o, 64);
    }
    if (lane == 0) { red[w * 2] = ss; red[w * 2 + 1] = sq; }
    __syncthreads();
    if (tid == 0) {
      double S = 0.0, Q = 0.0;
#pragma unroll
      for (int i = 0; i < 16; ++i) { S += red[i * 2]; Q += red[i * 2 + 1]; }
      const double m = S / cnt;
      double var = (Q - S * S / cnt) / (cnt - 1.0);
      if (var < 0.0) var = 0.0;
      bc[0] = (float)m;
      bc[1] = (float)(1.0 / (sqrt(var) + 1e-5));
    }
    __syncthreads();
  };

  // ================= PHASE E: embed =================
  {
    const float* fb = feature + (size_t)b * 16384;
#pragma unroll
    for (int it = 0; it < 4; ++it) {
      const int t = it * 1024 + tid;
      const int d = t >> 5;
      const int c4 = (t & 31) * 4;
      const float4 v = *reinterpret_cast<const float4*>(&fb[d * 128 + c4]);
      float* p = &feat[d * 133 + c4];
      p[0] = v.x; p[1] = v.y; p[2] = v.z; p[3] = v.w;
    }
    const float4* s = (const float4*)col_embed;
    float4* d4 = (float4*)ceL;
#pragma unroll
    for (int it = 0; it < 2; ++it) {
      const int t = it * 1024 + tid;
      if (t < 1600) d4[t] = s[t];
    }
    if (tid < 160) ((float4*)oeL)[tid] = ((const float4*)op_embed)[tid];
    if (tid < NIDX) nb_s[tid] = idx[b * NIDX + tid];
  }
  __syncthreads();

  // E2: per wave 8 nodes -> collate fragments in registers
  float emb[8], oth[8], par[8];
#pragma unroll
  for (int ni = 0; ni < 8; ++ni) {
    const int n = w * 8 + ni;
    int civ = 0, oiv = 0;
    if (lane < MAXP) civ = (int)feat[(OTHER_ + lane) * 133 + n];
    if (lane >= 32 && lane < 32 + MAXP) oiv = (int)feat[(OTHER_ + MAXP + (lane - 32)) * 133 + n];
    const int L = (int)feat[95 * 133 + n];
    float acc = 0.f;
    for (int i = 0; i < L; ++i) {
      const int cv = __shfl(civ, i);
      const int ov = __shfl(oiv, 32 + i);
      acc += (lane < 32) ? ceL[cv * 32 + cl] : oeL[ov * 32 + cl];
    }
    emb[ni] = acc;
    oth[ni] = (lane < 35) ? feat[lane * 133 + n] : 0.f;
    par[ni] = (lane < 32) ? feat[(96 + lane) * 133 + n] : 0.f;
  }
  int nbr[2][3];
#pragma unroll
  for (int jt = 0; jt < 2; ++jt) {
    const int jA = jbase + jt * 16 + col;
#pragma unroll
    for (int kk = 0; kk < 3; ++kk)
      nbr[jt][kk] = (jA > 0) ? nb_s[(jA - 1) * 3 + kk] : 0;
  }
  __syncthreads();   // all feat/table reads done; region reusable

  // E3: write collate (split bf16) into sH/sL rows
#pragma unroll
  for (int ni = 0; ni < 8; ++ni) {
    const int n = w * 8 + ni;
    const int base = n * CINP;
    short h, l;
    split2(emb[ni], h, l);
    sH[base + 35 + lane] = h; sL[base + 35 + lane] = l;
    if (lane < 35) {
      split2(oth[ni], h, l);
      sH[base + lane] = h; sL[base + lane] = l;
    }
    if (lane < 32) {
      split2(par[ni], h, l);
      sH[base + 99 + lane] = h; sL[base + 99 + lane] = l;
    }
    if (lane < 29) { sH[base + 131 + lane] = 0; sL[base + 131 + lane] = 0; }
  }
  __syncthreads();

  // ================= conv1: COUT 256, SUB=4 =================
  f32x4 a1[2][4];
#pragma unroll
  for (int jt = 0; jt < 2; ++jt)
#pragma unroll
    for (int su = 0; su < 4; ++su) {
      a1[jt][su][0] = 0.f; a1[jt][su][1] = 0.f;
      a1[jt][su][2] = 0.f; a1[jt][su][3] = 0.f;
    }

#pragma unroll
  for (int kk = 0; kk < 3; ++kk) {
#pragma unroll
    for (int ks = 0; ks < 5; ++ks) {
      const int gks = kk * 5 + ks;
      short8 ah[2], al[2];
#pragma unroll
      for (int jt = 0; jt < 2; ++jt) {
        const int ei = nbr[jt][kk] * CINP + ks * 32 + grp * 8;
        ah[jt] = *reinterpret_cast<const short8*>(&sH[ei]);
        al[jt] = *reinterpret_cast<const short8*>(&sL[ei]);
      }
      short8 bh[4], bl[4];
#pragma unroll
      for (int su = 0; su < 4; ++su) {
        const int wi = ((gks * 4 + wo) * 4 + su) * 64 + lane;
        bh[su] = wp1h[wi];
        bl[su] = wp1l[wi];
      }
#pragma unroll
      for (int jt = 0; jt < 2; ++jt)
#pragma unroll
        for (int su = 0; su < 4; ++su) {
          a1[jt][su] = __builtin_amdgcn_mfma_f32_16x16x32_bf16(ah[jt], bh[su], a1[jt][su], 0, 0, 0);
          a1[jt][su] = __builtin_amdgcn_mfma_f32_16x16x32_bf16(al[jt], bh[su], a1[jt][su], 0, 0, 0);
          a1[jt][su] = __builtin_amdgcn_mfma_f32_16x16x32_bf16(ah[jt], bl[su], a1[jt][su], 0, 0, 0);
        }
    }
  }

  // ---- epilogue1: bias, zero col j=0, stats ----
  {
    double ss = 0.0, sq = 0.0;
#pragma unroll
    for (int su = 0; su < 4; ++su) {
      const float bv = b1[(wo * 4 + su) * 16 + col];
#pragma unroll
      for (int jt = 0; jt < 2; ++jt)
#pragma unroll
        for (int r = 0; r < 4; ++r) {
          const int j = jbase + jt * 16 + grp * 4 + r;
          const float val = (j > 0) ? a1[jt][su][r] + bv : 0.f;
          a1[jt][su][r] = val;
          ss += (double)val;
          sq += (double)val * (double)val;
        }
    }
    blockStats(ss, sq, 256.0 * 128.0);
  }
  const float mean1 = bc[0], inv1 = bc[1];

  // ---- conv2 stage: all 256 ch from registers ----
#pragma unroll
  for (int su = 0; su < 4; ++su) {
    const int c = (wo * 4 + su) * 16 + col;
#pragma unroll
    for (int jt = 0; jt < 2; ++jt)
#pragma unroll
      for (int r = 0; r < 4; ++r) {
        const int j = jbase + jt * 16 + grp * 4 + r;
        float v = (a1[jt][su][r] - mean1) * inv1;
        v = fmaxf(v, 0.01f * v);
        short h, l;
        split2(v, h, l);
        sH[j * CINP + c] = h;
        sL[j * CINP + c] = l;
      }
  }
  __syncthreads();

  // ================= conv2: COUT 128, SUB=2 =================
  f32x4 a2[2][2];
#pragma unroll
  for (int jt = 0; jt < 2; ++jt)
#pragma unroll
    for (int su = 0; su < 2; ++su) {
      a2[jt][su][0] = 0.f; a2[jt][su][1] = 0.f;
      a2[jt][su][2] = 0.f; a2[jt][su][3] = 0.f;
    }

#pragma unroll
  for (int kk = 0; kk < 3; ++kk) {
#pragma unroll
    for (int ks = 0; ks < 8; ++ks) {
      const int gks = kk * 8 + ks;
      short8 ah[2], al[2];
#pragma unroll
      for (int jt = 0; jt < 2; ++jt) {
        const int ei = nbr[jt][kk] * CINP + ks * 32 + grp * 8;
        ah[jt] = *reinterpret_cast<const short8*>(&sH[ei]);
        al[jt] = *reinterpret_cast<const short8*>(&sL[ei]);
      }
      short8 bh[2], bl[2];
#pragma unroll
      for (int su = 0; su < 2; ++su) {
        const int wi = ((gks * 4 + wo) * 2 + su) * 64 + lane;
        bh[su] = wp2h[wi];
        bl[su] = wp2l[wi];
      }
#pragma unroll
      for (int jt = 0; jt < 2; ++jt)
#pragma unroll
        for (int su = 0; su < 2; ++su) {
          a2[jt][su] = __builtin_amdgcn_mfma_f32_16x16x32_bf16(ah[jt], bh[su], a2[jt][su], 0, 0, 0);
          a2[jt][su] = __builtin_amdgcn_mfma_f32_16x16x32_bf16(al[jt], bh[su], a2[jt][su], 0, 0, 0);
          a2[jt][su] = __builtin_amdgcn_mfma_f32_16x16x32_bf16(ah[jt], bl[su], a2[jt][su], 0, 0, 0);
        }
    }
  }

  // ---- epilogue2 ----
  {
    double ss = 0.0, sq = 0.0;
#pragma unroll
    for (int su = 0; su < 2; ++su) {
      const float bv = b2[(wo * 2 + su) * 16 + col];
#pragma unroll
      for (int jt = 0; jt < 2; ++jt)
#pragma unroll
        for (int r = 0; r < 4; ++r) {
          const int j = jbase + jt * 16 + grp * 4 + r;
          const float val = (j > 0) ? a2[jt][su][r] + bv : 0.f;
          a2[jt][su][r] = val;
          ss += (double)val;
          sq += (double)val * (double)val;
        }
    }
    blockStats(ss, sq, 128.0 * 128.0);
  }
  const float mean2 = bc[0], inv2 = bc[1];

  // ---- conv3 stage: all 128 ch ----
#pragma unroll
  for (int su = 0; su < 2; ++su) {
    const int c = (wo * 2 + su) * 16 + col;
#pragma unroll
    for (int jt = 0; jt < 2; ++jt)
#pragma unroll
      for (int r = 0; r < 4; ++r) {
        const int j = jbase + jt * 16 + grp * 4 + r;
        float v = (a2[jt][su][r] - mean2) * inv2;
        v = fmaxf(v, 0.01f * v);
        short h, l;
        split2(v, h, l);
        sH[j * CINP + c] = h;
        sL[j * CINP + c] = l;
      }
  }
  __syncthreads();

  // ================= conv3: COUT 64, SUB=1 =================
  f32x4 a3[2];
#pragma unroll
  for (int jt = 0; jt < 2; ++jt) {
    a3[jt][0] = 0.f; a3[jt][1] = 0.f; a3[jt][2] = 0.f; a3[jt][3] = 0.f;
  }

#pragma unroll
  for (int kk = 0; kk < 3; ++kk) {
#pragma unroll
    for (int ks = 0; ks < 4; ++ks) {
      const int gks = kk * 4 + ks;
      short8 ah[2], al[2];
#pragma unroll
      for (int jt = 0; jt < 2; ++jt) {
        const int ei = nbr[jt][kk] * CINP + ks * 32 + grp * 8;
        ah[jt] = *reinterpret_cast<const short8*>(&sH[ei]);
        al[jt] = *reinterpret_cast<const short8*>(&sL[ei]);
      }
      short8 bh, bl;
      {
        const int wi = (gks * 4 + wo) * 64 + lane;
        bh = wp3h[wi];
        bl = wp3l[wi];
      }
#pragma unroll
      for (int jt = 0; jt < 2; ++jt) {
        a3[jt] = __builtin_amdgcn_mfma_f32_16x16x32_bf16(ah[jt], bh, a3[jt], 0, 0, 0);
        a3[jt] = __builtin_amdgcn_mfma_f32_16x16x32_bf16(al[jt], bh, a3[jt], 0, 0, 0);
        a3[jt] = __builtin_amdgcn_mfma_f32_16x16x32_bf16(ah[jt], bl, a3[jt], 0, 0, 0);
      }
    }
  }

  // ---- epilogue3 + stats ----
  {
    double ss = 0.0, sq = 0.0;
    const float bv = b3[wo * 16 + col];
#pragma unroll
    for (int jt = 0; jt < 2; ++jt)
#pragma unroll
      for (int r = 0; r < 4; ++r) {
        const int j = jbase + jt * 16 + grp * 4 + r;
        const float val = (j > 0) ? a3[jt][r] + bv : 0.f;
        a3[jt][r] = val;
        ss += (double)val;
        sq += (double)val * (double)val;
      }
    blockStats(ss, sq, 64.0 * 128.0);
  }
  const float mean3 = bc[0], inv3 = bc[1];

  // ---- maxpool over this wave's j-range, then cross-wj in LDS ----
  {
    float pm = -3.4e38f;
#pragma unroll
    for (int jt = 0; jt < 2; ++jt)
#pragma unroll
      for (int r = 0; r < 4; ++r)
        pm = fmaxf(pm, (a3[jt][r] - mean3) * inv3);
    pm = fmaxf(pm, __shfl_xor(pm, 16, 64));
    pm = fmaxf(pm, __shfl_xor(pm, 32, 64));
    if (lane < 16) poolw[w][col] = pm;
  }
  __syncthreads();

  // ---- 2-layer MLP (wave 0) ----
  if (w == 0) {
    float hval = 0.f;
    if (lane < 32) {
      float a = fb1[lane];
#pragma unroll 8
      for (int c = 0; c < 64; ++c) {
        const int oq = c >> 4, oc16 = c & 15;
        float p = poolw[oq][oc16];
#pragma unroll
        for (int jw = 1; jw < 4; ++jw) p = fmaxf(p, poolw[jw * 4 + oq][oc16]);
        a = fmaf(p, fw1[lane * 64 + c], a);
      }
      hval = fmaxf(a, 0.f) * fw2[lane];
    }
#pragma unroll
    for (int o = 32; o > 0; o >>= 1) hval += __shfl_down(hval, o, 64);
    if (lane == 0) out[b] = hval + fb2[0];
  }
}

// ---------------------------------------------------------------------------
extern "C" void kernel_launch(void* const* d_in, const int* in_sizes, int n_in,
                              void* d_out, int out_size, void* d_ws, size_t ws_size,
                              hipStream_t stream) {
  const float* feature   = (const float*)d_in[0];
  const void*  indexes   = d_in[1];
  const float* col_embed = (const float*)d_in[2];
  const float* op_embed  = (const float*)d_in[3];
  const float* w1  = (const float*)d_in[4];
  const float* b1  = (const float*)d_in[5];
  const float* w2  = (const float*)d_in[6];
  const float* b2  = (const float*)d_in[7];
  const float* w3  = (const float*)d_in[8];
  const float* b3  = (const float*)d_in[9];
  const float* fw1 = (const float*)d_in[10];
  const float* fb1 = (const float*)d_in[11];
  const float* fw2 = (const float*)d_in[12];
  const float* fb2 = (const float*)d_in[13];
  float* out = (float*)d_out;

  char* ws = (char*)d_ws;
  size_t off = 0;
  auto carve = [&](size_t bytes) -> char* {
    off = (off + 255) & ~(size_t)255;
    char* p = ws + off;
    off += bytes;
    return p;
  };
  int*   idx32 = (int*)carve((size_t)S_IDX * sizeof(int));
  short* w1h   = (short*)carve((size_t)S_P1 * sizeof(short));
  short* w1l   = (short*)carve((size_t)S_P1 * sizeof(short));
  short* w2h   = (short*)carve((size_t)S_P2 * sizeof(short));
  short* w2l   = (short*)carve((size_t)S_P2 * sizeof(short));
  short* w3h   = (short*)carve((size_t)S_P3 * sizeof(short));
  short* w3l   = (short*)carve((size_t)S_P3 * sizeof(short));
  (void)ws_size; (void)in_sizes; (void)n_in; (void)out_size;

  hipLaunchKernelGGL(prep_kernel, dim3(PREP_BLOCKS), dim3(512), 0, stream,
                     indexes, idx32, w1, w1h, w1l, w2, w2h, w2l, w3, w3h, w3l);
  hipLaunchKernelGGL(fused_kernel, dim3(B_), dim3(1024), 0, stream,
                     feature, col_embed, op_embed, idx32,
                     w1h, w1l, w2h, w2l, w3h, w3l,
                     b1, b2, b3, fw1, fb1, fw2, fb2, out);
}